// Round 2
// baseline (567.770 us; speedup 1.0000x reference)
//
#include <hip/hip_runtime.h>
#include <math.h>

typedef __bf16 bf16x8 __attribute__((ext_vector_type(8)));
typedef float f32x4 __attribute__((ext_vector_type(4)));

// ---- constants for this problem ----
#define BATCH 2
#define SEQ   2048
#define DMODEL 1024
#define NHEAD 16
#define DHEAD 64
#define MROWS (BATCH*SEQ)       // 4096
#define N_QKV (3*DMODEL)        // 3072
#define OUTSECT (MROWS*DMODEL)  // 4194304 elements per output section

__device__ inline __bf16 f2bf(float f) {
    unsigned u = __builtin_bit_cast(unsigned, f);
    unsigned r = (u + 0x7fffu + ((u >> 16) & 1u)) >> 16;
    return __builtin_bit_cast(__bf16, (unsigned short)r);
}

__device__ inline void st4(__bf16* p, float4 v) {
    p[0] = f2bf(v.x); p[1] = f2bf(v.y); p[2] = f2bf(v.z); p[3] = f2bf(v.w);
}

#define BM 128
#define BN 128
#define BK 64
#define LDK 72   // padded LDS stride: 144B, 16B-aligned, 2-way bank conflict (free)

// MODE 0: qkv gemm -> scatter q to ws, k/v to d_out sections (layout [B,H,L,Dh])
// MODE 1: plain out gemm -> o0[row*N + col]
template<int MODE>
__global__ __launch_bounds__(256)
void gemm_k(const float* __restrict__ A, const float* __restrict__ Bm,
            const float* __restrict__ bias,
            float* __restrict__ o0, float* __restrict__ o1, float* __restrict__ o2,
            int M, int N, int K)
{
    __shared__ __bf16 As[BM][LDK];
    __shared__ __bf16 Bs[BN][LDK];   // transposed: Bs[n][k]

    const int tid = threadIdx.x;
    const int wid = tid >> 6;
    const int lane = tid & 63;
    const int l16 = lane & 15;
    const int lq  = lane >> 4;
    const int wm = wid >> 1, wn = wid & 1;
    const int m0 = blockIdx.y * BM;
    const int n0 = blockIdx.x * BN;

    f32x4 acc[4][4];
    #pragma unroll
    for (int i = 0; i < 4; ++i)
        #pragma unroll
        for (int j = 0; j < 4; ++j)
            acc[i][j] = f32x4{0.f, 0.f, 0.f, 0.f};

    for (int k0 = 0; k0 < K; k0 += BK) {
        __syncthreads();
        // stage A tile: 128 x 64 f32 -> bf16
        #pragma unroll
        for (int u = 0; u < 8; ++u) {
            int idx = tid + 256 * u;           // 0..2047
            int r   = idx >> 4;                // 0..127
            int c4  = (idx & 15) << 2;         // 0..60
            float4 va = *reinterpret_cast<const float4*>(&A[(size_t)(m0 + r) * K + k0 + c4]);
            st4(&As[r][c4], va);
        }
        // stage B tile transposed: 64 x 128 f32 -> Bs[n][k]
        #pragma unroll
        for (int u = 0; u < 8; ++u) {
            int idx = tid + 256 * u;
            int kr  = idx >> 5;                // 0..63
            int c4  = (idx & 31) << 2;         // 0..124
            float4 vb = *reinterpret_cast<const float4*>(&Bm[(size_t)(k0 + kr) * N + n0 + c4]);
            Bs[c4 + 0][kr] = f2bf(vb.x);
            Bs[c4 + 1][kr] = f2bf(vb.y);
            Bs[c4 + 2][kr] = f2bf(vb.z);
            Bs[c4 + 3][kr] = f2bf(vb.w);
        }
        __syncthreads();
        #pragma unroll
        for (int kk = 0; kk < 2; ++kk) {
            bf16x8 af[4], bfg[4];
            #pragma unroll
            for (int i = 0; i < 4; ++i)
                af[i] = *reinterpret_cast<const bf16x8*>(&As[wm * 64 + i * 16 + l16][kk * 32 + lq * 8]);
            #pragma unroll
            for (int j = 0; j < 4; ++j)
                bfg[j] = *reinterpret_cast<const bf16x8*>(&Bs[wn * 64 + j * 16 + l16][kk * 32 + lq * 8]);
            #pragma unroll
            for (int i = 0; i < 4; ++i)
                #pragma unroll
                for (int j = 0; j < 4; ++j)
                    acc[i][j] = __builtin_amdgcn_mfma_f32_16x16x32_bf16(af[i], bfg[j], acc[i][j], 0, 0, 0);
        }
    }

    #pragma unroll
    for (int i = 0; i < 4; ++i) {
        #pragma unroll
        for (int j = 0; j < 4; ++j) {
            #pragma unroll
            for (int r = 0; r < 4; ++r) {
                int row = m0 + wm * 64 + i * 16 + lq * 4 + r;
                int col = n0 + wn * 64 + j * 16 + l16;
                float val = acc[i][j][r] + bias[col];
                if (MODE == 0) {
                    int which = col >> 10;
                    int rem = col & 1023;
                    int h = rem >> 6, dh = rem & 63;
                    int bb = row >> 11, ll = row & 2047;
                    size_t didx = (((size_t)(bb * NHEAD + h)) * SEQ + ll) * DHEAD + dh;
                    if (which == 0)      o0[didx] = val;
                    else if (which == 1) o1[didx] = val;
                    else                 o2[didx] = val;
                } else {
                    o0[(size_t)row * N + col] = val;
                }
            }
        }
    }
}

// Flash attention with ALiBi + causal.  Q,K,V in [B,H,L,Dh] f32.
// Output written to ws in [B,L,D] layout for the final GEMM.
__global__ __launch_bounds__(256)
void attn_k(const float* __restrict__ Q, const float* __restrict__ Kc,
            const float* __restrict__ Vc, float* __restrict__ O)
{
    __shared__ __bf16 Qs[64][LDK];
    __shared__ __bf16 Ks[64][LDK];
    __shared__ __bf16 Vt[64][LDK];      // transposed: Vt[dh][kvrow]
    __shared__ __bf16 Ps[4][16][LDK];   // per-wave P strip

    const int tid = threadIdx.x;
    const int wid = tid >> 6;
    const int lane = tid & 63;
    const int l16 = lane & 15;
    const int lq  = lane >> 4;
    const int qt = blockIdx.x;          // 0..31  q-tile
    const int bh = blockIdx.y;          // 0..31  b*16+h
    const int h  = bh & 15;
    const int bb = bh >> 4;
    const int q0 = qt * 64;
    const size_t base = (size_t)bh * SEQ * DHEAD;
    const float slope = exp2f(-0.5f * (float)(h + 1));
    const int qr0 = wid * 16;

    // load Q tile (64 x 64)
    #pragma unroll
    for (int u = 0; u < 4; ++u) {
        int idx = tid + 256 * u;        // 0..1023
        int r = idx >> 4;               // 0..63
        int c4 = (idx & 15) << 2;       // 0..60
        float4 v = *reinterpret_cast<const float4*>(&Q[base + (size_t)(q0 + r) * DHEAD + c4]);
        st4(&Qs[r][c4], v);
    }

    float mrow[4], lrow[4];
    f32x4 accO[4];
    #pragma unroll
    for (int r = 0; r < 4; ++r) { mrow[r] = -1e30f; lrow[r] = 0.f; }
    #pragma unroll
    for (int j = 0; j < 4; ++j) accO[j] = f32x4{0.f, 0.f, 0.f, 0.f};

    for (int jt = 0; jt <= qt; ++jt) {
        const int j0 = jt * 64;
        __syncthreads();
        #pragma unroll
        for (int u = 0; u < 4; ++u) {
            int idx = tid + 256 * u;
            int r = idx >> 4;
            int c4 = (idx & 15) << 2;
            float4 kv = *reinterpret_cast<const float4*>(&Kc[base + (size_t)(j0 + r) * DHEAD + c4]);
            st4(&Ks[r][c4], kv);
            float4 vv = *reinterpret_cast<const float4*>(&Vc[base + (size_t)(j0 + r) * DHEAD + c4]);
            Vt[c4 + 0][r] = f2bf(vv.x);
            Vt[c4 + 1][r] = f2bf(vv.y);
            Vt[c4 + 2][r] = f2bf(vv.z);
            Vt[c4 + 3][r] = f2bf(vv.w);
        }
        __syncthreads();

        // S = (Q K^T) for this wave's 16 q-rows, 64 kv-cols
        f32x4 s[4];
        #pragma unroll
        for (int nf = 0; nf < 4; ++nf) s[nf] = f32x4{0.f, 0.f, 0.f, 0.f};
        bf16x8 aq0 = *reinterpret_cast<const bf16x8*>(&Qs[qr0 + l16][lq * 8]);
        bf16x8 aq1 = *reinterpret_cast<const bf16x8*>(&Qs[qr0 + l16][32 + lq * 8]);
        #pragma unroll
        for (int nf = 0; nf < 4; ++nf) {
            bf16x8 bk0 = *reinterpret_cast<const bf16x8*>(&Ks[nf * 16 + l16][lq * 8]);
            bf16x8 bk1 = *reinterpret_cast<const bf16x8*>(&Ks[nf * 16 + l16][32 + lq * 8]);
            s[nf] = __builtin_amdgcn_mfma_f32_16x16x32_bf16(aq0, bk0, s[nf], 0, 0, 0);
            s[nf] = __builtin_amdgcn_mfma_f32_16x16x32_bf16(aq1, bk1, s[nf], 0, 0, 0);
        }

        // bias + mask + online softmax
        #pragma unroll
        for (int r = 0; r < 4; ++r) {
            int qi = q0 + qr0 + lq * 4 + r;
            float rm = -1e30f;
            #pragma unroll
            for (int nf = 0; nf < 4; ++nf) {
                int ki = j0 + nf * 16 + l16;
                float sc = s[nf][r] * 0.125f;
                sc = (ki <= qi) ? (sc + slope * (float)(ki - qi)) : -1e30f;
                s[nf][r] = sc;
                rm = fmaxf(rm, sc);
            }
            #pragma unroll
            for (int msk = 1; msk < 16; msk <<= 1)
                rm = fmaxf(rm, __shfl_xor(rm, msk));
            float mnew = fmaxf(mrow[r], rm);
            float rsum = 0.f;
            #pragma unroll
            for (int nf = 0; nf < 4; ++nf) {
                float p = __expf(s[nf][r] - mnew);
                Ps[wid][lq * 4 + r][nf * 16 + l16] = f2bf(p);
                rsum += p;
            }
            #pragma unroll
            for (int msk = 1; msk < 16; msk <<= 1)
                rsum += __shfl_xor(rsum, msk);
            float scale = __expf(mrow[r] - mnew);
            lrow[r] = lrow[r] * scale + rsum;
            mrow[r] = mnew;
            #pragma unroll
            for (int nf = 0; nf < 4; ++nf) accO[nf][r] *= scale;
        }

        // O += P V
        bf16x8 ap0 = *reinterpret_cast<const bf16x8*>(&Ps[wid][l16][lq * 8]);
        bf16x8 ap1 = *reinterpret_cast<const bf16x8*>(&Ps[wid][l16][32 + lq * 8]);
        #pragma unroll
        for (int nf = 0; nf < 4; ++nf) {
            bf16x8 bv0 = *reinterpret_cast<const bf16x8*>(&Vt[nf * 16 + l16][lq * 8]);
            bf16x8 bv1 = *reinterpret_cast<const bf16x8*>(&Vt[nf * 16 + l16][32 + lq * 8]);
            accO[nf] = __builtin_amdgcn_mfma_f32_16x16x32_bf16(ap0, bv0, accO[nf], 0, 0, 0);
            accO[nf] = __builtin_amdgcn_mfma_f32_16x16x32_bf16(ap1, bv1, accO[nf], 0, 0, 0);
        }
    }

    // write O (divide by l) into ws in [B, L, D] layout
    #pragma unroll
    for (int nf = 0; nf < 4; ++nf) {
        #pragma unroll
        for (int r = 0; r < 4; ++r) {
            int qi = q0 + qr0 + lq * 4 + r;
            int dh = nf * 16 + l16;
            O[((size_t)(bb * SEQ + qi)) * DMODEL + h * DHEAD + dh] = accO[nf][r] / lrow[r];
        }
    }
}

extern "C" void kernel_launch(void* const* d_in, const int* in_sizes, int n_in,
                              void* d_out, int out_size, void* d_ws, size_t ws_size,
                              hipStream_t stream) {
    const float* x     = (const float*)d_in[0];
    const float* W_in  = (const float*)d_in[1];
    const float* b_in  = (const float*)d_in[2];
    const float* W_out = (const float*)d_in[3];
    const float* b_out = (const float*)d_in[4];

    float* out  = (float*)d_out;            // [B,L,D]
    float* kout = out + OUTSECT;            // [B,H,L,Dh]
    float* vout = out + 2 * (size_t)OUTSECT;

    float* qws = (float*)d_ws;              // [B,H,L,Dh] 16MB
    float* aws = qws + OUTSECT;             // [B,L,D]    16MB

    // qkv = x @ W_in + b_in, scattered to q(ws), k(d_out), v(d_out)
    gemm_k<0><<<dim3(N_QKV / BN, MROWS / BM), 256, 0, stream>>>(
        x, W_in, b_in, qws, kout, vout, MROWS, N_QKV, DMODEL);

    // flash attention -> aws [B,L,D]
    attn_k<<<dim3(SEQ / 64, BATCH * NHEAD), 256, 0, stream>>>(qws, kout, vout, aws);

    // out = aws @ W_out + b_out
    gemm_k<1><<<dim3(DMODEL / BN, MROWS / BM), 256, 0, stream>>>(
        aws, W_out, b_out, out, nullptr, nullptr, MROWS, DMODEL, DMODEL);
}

// Round 3
// 262.559 us; speedup vs baseline: 2.1625x; 2.1625x over previous
//
#include <hip/hip_runtime.h>
#include <math.h>

typedef __bf16 bf16x8 __attribute__((ext_vector_type(8)));
typedef float  f32x4  __attribute__((ext_vector_type(4)));
typedef unsigned short u16x4 __attribute__((ext_vector_type(4)));

#define BATCH  2
#define SEQ    2048
#define DMODEL 1024
#define NHEAD  16
#define DHEAD  64
#define MROWS  4096
#define N_QKV  3072
#define KDIM   1024
#define OUTSECT (MROWS*DMODEL)   // 4194304 elements

__device__ inline __bf16 f2bf(float f) {
    unsigned u = __builtin_bit_cast(unsigned, f);
    unsigned r = (u + 0x7fffu + ((u >> 16) & 1u)) >> 16;
    return __builtin_bit_cast(__bf16, (unsigned short)r);
}

// async global->LDS, 16B per lane; LDS dest is wave-uniform base + lane*16
__device__ inline void gload16(const void* g, void* l) {
    __builtin_amdgcn_global_load_lds(
        (const __attribute__((address_space(1))) void*)g,
        (__attribute__((address_space(3))) void*)l, 16, 0, 0);
}

// ---------------- conversion kernels (run once per launch) ----------------

// f32 -> bf16 straight copy, 8 elems/thread
__global__ __launch_bounds__(256) void cvt_x_k(const float* __restrict__ x,
                                               __bf16* __restrict__ xb) {
    size_t i = (size_t)blockIdx.x * 256 + threadIdx.x;
    const float4* p = (const float4*)x + i * 2;
    float4 a = p[0], b = p[1];
    __bf16 o[8] = {f2bf(a.x), f2bf(a.y), f2bf(a.z), f2bf(a.w),
                   f2bf(b.x), f2bf(b.y), f2bf(b.z), f2bf(b.w)};
    *(bf16x8*)(xb + i * 8) = *(bf16x8*)o;
}

// W [KDIM][Nw] f32 -> Wt [Nw][KDIM] bf16 (LDS-tiled transpose)
__global__ __launch_bounds__(256) void cvt_wt_k(const float* __restrict__ W,
                                                __bf16* __restrict__ Wt, int Nw) {
    __shared__ float t[64][65];
    const int k0 = blockIdx.y * 64, n0 = blockIdx.x * 64;
    const int tid = threadIdx.x;
    #pragma unroll
    for (int u = 0; u < 4; ++u) {
        int idx = u * 256 + tid;
        int r = idx >> 4, c4 = (idx & 15) << 2;
        float4 v = *(const float4*)&W[(size_t)(k0 + r) * Nw + n0 + c4];
        t[r][c4] = v.x; t[r][c4 + 1] = v.y; t[r][c4 + 2] = v.z; t[r][c4 + 3] = v.w;
    }
    __syncthreads();
    #pragma unroll
    for (int u = 0; u < 2; ++u) {
        int idx = u * 256 + tid;
        int n = idx >> 3, k8 = (idx & 7) << 3;
        __bf16 o[8];
        #pragma unroll
        for (int i = 0; i < 8; ++i) o[i] = f2bf(t[k8 + i][n]);
        *(bf16x8*)&Wt[(size_t)(n0 + n) * KDIM + k0 + k8] = *(bf16x8*)o;
    }
}

// ---------------- GEMM: A[M][1024] bf16 row-major, Bt[N][1024] bf16 row-major
// m97 structure: global_load_lds(16B) staging, XOR-swizzled LDS, 16x16x32 MFMA.
// MODE 0: qkv epilogue (q->qb, k->kf+kb, v->vf+vbT)   MODE 1: plain f32 out
template<int MODE, int FI, int FJ>
__global__ __launch_bounds__(256) void gemm_bf(
    const __bf16* __restrict__ A, const __bf16* __restrict__ Bt,
    const float* __restrict__ bias,
    float* __restrict__ fo, float* __restrict__ kf, float* __restrict__ vf,
    __bf16* __restrict__ qb, __bf16* __restrict__ kb, __bf16* __restrict__ vb,
    int nbx)
{
    constexpr int BMt = FI * 32, BNt = FJ * 32;
    __shared__ __align__(16) __bf16 As[BMt * 64];
    __shared__ __align__(16) __bf16 Bs[BNt * 64];

    const int tid = threadIdx.x, wid = tid >> 6, lane = tid & 63;
    const int l16 = lane & 15, lq = lane >> 4;
    const int wm = wid >> 1, wn = wid & 1;

    // bijective XCD swizzle (gridDim.x % 8 == 0)
    const int nwg = gridDim.x;
    const int bid = blockIdx.x;
    const int swz = (bid & 7) * (nwg >> 3) + (bid >> 3);
    const int m0 = (swz / nbx) * BMt;
    const int n0 = (swz % nbx) * BNt;

    const int lr8 = lane >> 3;                      // row-within-chunk
    const int colE = ((lane & 7) ^ lr8) << 3;       // pre-swizzled source col (elems)

    f32x4 acc[FI][FJ];
    #pragma unroll
    for (int i = 0; i < FI; ++i)
        #pragma unroll
        for (int j = 0; j < FJ; ++j)
            acc[i][j] = f32x4{0.f, 0.f, 0.f, 0.f};

    for (int k0 = 0; k0 < KDIM; k0 += 64) {
        __syncthreads();
        #pragma unroll
        for (int c = wid; c < FI * 4 + FJ * 4; c += 4) {
            const bool isA = (c < FI * 4);          // wave-uniform (FI*4 % 4 == 0)
            const int ch = isA ? c : c - FI * 4;
            const int row = ch * 8 + lr8;
            const __bf16* src = isA ? (A  + (size_t)(m0 + row) * KDIM + k0 + colE)
                                    : (Bt + (size_t)(n0 + row) * KDIM + k0 + colE);
            gload16(src, (isA ? As : Bs) + ch * 512);
        }
        __syncthreads();
        #pragma unroll
        for (int kk = 0; kk < 2; ++kk) {
            bf16x8 af[FI], bfg[FJ];
            #pragma unroll
            for (int i = 0; i < FI; ++i) {
                int r = wm * (FI * 16) + i * 16 + l16;
                af[i] = *(const bf16x8*)&As[r * 64 + ((kk * 32 + lq * 8) ^ ((r & 7) << 3))];
            }
            #pragma unroll
            for (int j = 0; j < FJ; ++j) {
                int r = wn * (FJ * 16) + j * 16 + l16;
                bfg[j] = *(const bf16x8*)&Bs[r * 64 + ((kk * 32 + lq * 8) ^ ((r & 7) << 3))];
            }
            #pragma unroll
            for (int i = 0; i < FI; ++i)
                #pragma unroll
                for (int j = 0; j < FJ; ++j)
                    acc[i][j] = __builtin_amdgcn_mfma_f32_16x16x32_bf16(af[i], bfg[j], acc[i][j], 0, 0, 0);
        }
    }

    #pragma unroll
    for (int i = 0; i < FI; ++i) {
        #pragma unroll
        for (int j = 0; j < FJ; ++j) {
            const int col  = n0 + wn * (FJ * 16) + j * 16 + l16;
            const int rowb = m0 + wm * (FI * 16) + i * 16 + lq * 4;
            float v[4];
            #pragma unroll
            for (int r = 0; r < 4; ++r) v[r] = acc[i][j][r] + bias[col];
            if (MODE == 1) {
                #pragma unroll
                for (int r = 0; r < 4; ++r)
                    fo[(size_t)(rowb + r) * DMODEL + col] = v[r];
            } else {
                const int which = col >> 10, rem = col & 1023;
                const int h = rem >> 6, dh = rem & 63;
                const int bb = rowb >> 11, ll = rowb & 2047;   // rowb..+3 same bb
                const size_t lidx = ((size_t)(bb * NHEAD + h) * SEQ + ll) * DHEAD + dh;
                if (which == 0) {
                    #pragma unroll
                    for (int r = 0; r < 4; ++r) qb[lidx + (size_t)r * DHEAD] = f2bf(v[r]);
                } else if (which == 1) {
                    #pragma unroll
                    for (int r = 0; r < 4; ++r) {
                        kf[lidx + (size_t)r * DHEAD] = v[r];
                        kb[lidx + (size_t)r * DHEAD] = f2bf(v[r]);
                    }
                } else {
                    u16x4 pk;
                    #pragma unroll
                    for (int r = 0; r < 4; ++r) {
                        vf[lidx + (size_t)r * DHEAD] = v[r];
                        pk[r] = __builtin_bit_cast(unsigned short, f2bf(v[r]));
                    }
                    // transposed bf16 V: [B,H,Dh,L], r-consecutive -> packed 8B store
                    *(u16x4*)&vb[((size_t)(bb * NHEAD + h) * DHEAD + dh) * SEQ + ll] = pk;
                }
            }
        }
    }
}

// ---------------- flash attention: Qb,Kb [B,H,L,Dh] bf16, Vb [B,H,Dh,L] bf16
__global__ __launch_bounds__(256) void attn_k(
    const __bf16* __restrict__ Qb, const __bf16* __restrict__ Kb,
    const __bf16* __restrict__ Vb, __bf16* __restrict__ Ob)
{
    __shared__ __align__(16) __bf16 Qs[64 * 64];
    __shared__ __align__(16) __bf16 Ks[64 * 64];
    __shared__ __align__(16) __bf16 Vs[64 * 64];   // [dh][kv]
    __shared__ __align__(16) __bf16 Ps[4 * 16 * 64];

    const int tid = threadIdx.x, wid = tid >> 6, lane = tid & 63;
    const int l16 = lane & 15, lq = lane >> 4;
    // swizzle so 4 consecutive bh (2MB of K/V) stay on one XCD
    const int nwg = 1024;
    const int bid = blockIdx.y * gridDim.x + blockIdx.x;
    const int swz = (bid & 7) * (nwg >> 3) + (bid >> 3);
    const int qt = swz & 31, bh = swz >> 5;
    const int h = bh & 15, bb = bh >> 4;
    const int q0 = qt * 64;
    const size_t kvbase = (size_t)bh * SEQ * DHEAD;
    const float slope = exp2f(-0.5f * (float)(h + 1));
    const int qr0 = wid * 16;
    const int lr8 = lane >> 3;
    const int colE = ((lane & 7) ^ lr8) << 3;

    // stage Q (8 chunks of 8 rows)
    #pragma unroll
    for (int u = 0; u < 2; ++u) {
        int ch = u * 4 + wid;
        int row = ch * 8 + lr8;
        gload16(Qb + kvbase + (size_t)(q0 + row) * DHEAD + colE, Qs + ch * 512);
    }

    float mrow[4], lrow[4];
    f32x4 accO[4];
    #pragma unroll
    for (int r = 0; r < 4; ++r) { mrow[r] = -1e30f; lrow[r] = 0.f; }
    #pragma unroll
    for (int j = 0; j < 4; ++j) accO[j] = f32x4{0.f, 0.f, 0.f, 0.f};

    for (int jt = 0; jt <= qt; ++jt) {
        const int j0 = jt * 64;
        __syncthreads();
        #pragma unroll
        for (int u = 0; u < 2; ++u) {
            int ch = u * 4 + wid;
            int row = ch * 8 + lr8;
            gload16(Kb + kvbase + (size_t)(j0 + row) * DHEAD + colE, Ks + ch * 512);
            gload16(Vb + kvbase + (size_t)row * SEQ + j0 + colE,     Vs + ch * 512);
        }
        __syncthreads();

        // S = Q K^T  (per wave: 16 q-rows x 64 kv-cols)
        f32x4 s[4];
        #pragma unroll
        for (int nf = 0; nf < 4; ++nf) s[nf] = f32x4{0.f, 0.f, 0.f, 0.f};
        const int qrow = qr0 + l16;
        bf16x8 aq0 = *(const bf16x8*)&Qs[qrow * 64 + ((lq * 8) ^ ((qrow & 7) << 3))];
        bf16x8 aq1 = *(const bf16x8*)&Qs[qrow * 64 + ((32 + lq * 8) ^ ((qrow & 7) << 3))];
        __builtin_amdgcn_s_setprio(1);
        #pragma unroll
        for (int nf = 0; nf < 4; ++nf) {
            int kr = nf * 16 + l16;
            bf16x8 bk0 = *(const bf16x8*)&Ks[kr * 64 + ((lq * 8) ^ ((kr & 7) << 3))];
            bf16x8 bk1 = *(const bf16x8*)&Ks[kr * 64 + ((32 + lq * 8) ^ ((kr & 7) << 3))];
            s[nf] = __builtin_amdgcn_mfma_f32_16x16x32_bf16(aq0, bk0, s[nf], 0, 0, 0);
            s[nf] = __builtin_amdgcn_mfma_f32_16x16x32_bf16(aq1, bk1, s[nf], 0, 0, 0);
        }
        __builtin_amdgcn_s_setprio(0);

        // bias + causal mask + online softmax (per lq-group row)
        #pragma unroll
        for (int r = 0; r < 4; ++r) {
            const int qi = q0 + qr0 + lq * 4 + r;
            float rm = -1e30f;
            #pragma unroll
            for (int nf = 0; nf < 4; ++nf) {
                int ki = j0 + nf * 16 + l16;
                float sc = s[nf][r] * 0.125f;
                sc = (ki <= qi) ? (sc + slope * (float)(ki - qi)) : -1e30f;
                s[nf][r] = sc;
                rm = fmaxf(rm, sc);
            }
            #pragma unroll
            for (int msk = 1; msk < 16; msk <<= 1)
                rm = fmaxf(rm, __shfl_xor(rm, msk));
            float mnew = fmaxf(mrow[r], rm);
            float rsum = 0.f;
            const int prow = lq * 4 + r;
            #pragma unroll
            for (int nf = 0; nf < 4; ++nf) {
                float p = __expf(s[nf][r] - mnew);
                Ps[wid * 1024 + prow * 64 + ((nf * 16 + l16) ^ ((prow & 7) << 3))] = f2bf(p);
                rsum += p;
            }
            #pragma unroll
            for (int msk = 1; msk < 16; msk <<= 1)
                rsum += __shfl_xor(rsum, msk);
            float scale = __expf(mrow[r] - mnew);
            lrow[r] = lrow[r] * scale + rsum;
            mrow[r] = mnew;
            #pragma unroll
            for (int nf = 0; nf < 4; ++nf) accO[nf][r] *= scale;
        }

        // O += P V
        bf16x8 ap0 = *(const bf16x8*)&Ps[wid * 1024 + l16 * 64 + ((lq * 8) ^ ((l16 & 7) << 3))];
        bf16x8 ap1 = *(const bf16x8*)&Ps[wid * 1024 + l16 * 64 + ((32 + lq * 8) ^ ((l16 & 7) << 3))];
        __builtin_amdgcn_s_setprio(1);
        #pragma unroll
        for (int nf = 0; nf < 4; ++nf) {
            int vr = nf * 16 + l16;
            bf16x8 bv0 = *(const bf16x8*)&Vs[vr * 64 + ((lq * 8) ^ ((vr & 7) << 3))];
            bf16x8 bv1 = *(const bf16x8*)&Vs[vr * 64 + ((32 + lq * 8) ^ ((vr & 7) << 3))];
            accO[nf] = __builtin_amdgcn_mfma_f32_16x16x32_bf16(ap0, bv0, accO[nf], 0, 0, 0);
            accO[nf] = __builtin_amdgcn_mfma_f32_16x16x32_bf16(ap1, bv1, accO[nf], 0, 0, 0);
        }
        __builtin_amdgcn_s_setprio(0);
    }

    // write O (bf16) into [B,L,D] for the out-proj GEMM
    #pragma unroll
    for (int nf = 0; nf < 4; ++nf) {
        #pragma unroll
        for (int r = 0; r < 4; ++r) {
            int qi = q0 + qr0 + lq * 4 + r;
            int dh = nf * 16 + l16;
            Ob[(size_t)(bb * SEQ + qi) * DMODEL + h * DHEAD + dh] = f2bf(accO[nf][r] / lrow[r]);
        }
    }
}

extern "C" void kernel_launch(void* const* d_in, const int* in_sizes, int n_in,
                              void* d_out, int out_size, void* d_ws, size_t ws_size,
                              hipStream_t stream) {
    const float* x     = (const float*)d_in[0];
    const float* W_in  = (const float*)d_in[1];
    const float* b_in  = (const float*)d_in[2];
    const float* W_out = (const float*)d_in[3];
    const float* b_out = (const float*)d_in[4];

    float* out = (float*)d_out;                    // section 0: final out (f32)
    float* kf  = out + (size_t)OUTSECT;            // section 1: k f32 [B,H,L,Dh]
    float* vf  = out + 2 * (size_t)OUTSECT;        // section 2: v f32 [B,H,L,Dh]

    // scratch inside d_out section 0 (dead before GEMM2 overwrites it):
    __bf16* qb = (__bf16*)d_out;                   // bytes [0, 8M): q bf16 [B,H,L,Dh]
    __bf16* xb = (__bf16*)d_out + (size_t)OUTSECT; // bytes [8M,16M): x bf16 [M][K]

    // ws: exactly 32 MB
    __bf16* ob  = (__bf16*)d_ws;                   // attn out bf16 [B,L,D]   8 MB
    __bf16* kb  = ob + (size_t)OUTSECT;            // k bf16 [B,H,L,Dh]       8 MB
    __bf16* vb  = kb + (size_t)OUTSECT;            // v bf16 [B,H,Dh,L]       8 MB
    __bf16* wti = vb + (size_t)OUTSECT;            // W_in^T bf16 [3072][1024] 6 MB
    __bf16* wto = wti + (size_t)N_QKV * KDIM;      // W_out^T bf16 [1024][1024] 2 MB

    cvt_x_k <<<2048, 256, 0, stream>>>(x, xb);
    cvt_wt_k<<<dim3(48, 16), 256, 0, stream>>>(W_in,  wti, N_QKV);
    cvt_wt_k<<<dim3(16, 16), 256, 0, stream>>>(W_out, wto, DMODEL);

    // qkv = x @ W_in + b_in  (128x128 tile), epilogue scatters q/k/v
    gemm_bf<0, 4, 4><<<768, 256, 0, stream>>>(xb, wti, b_in,
        nullptr, kf, vf, qb, kb, vb, N_QKV / 128);

    // flash attention
    attn_k<<<dim3(32, 32), 256, 0, stream>>>(qb, kb, vb, ob);

    // out = attn @ W_out + b_out  (64x128 tile -> 512 blocks)
    gemm_bf<1, 2, 4><<<512, 256, 0, stream>>>(ob, wto, b_out,
        out, nullptr, nullptr, nullptr, nullptr, nullptr, DMODEL / 128);
}

// Round 4
// 222.594 us; speedup vs baseline: 2.5507x; 1.1795x over previous
//
#include <hip/hip_runtime.h>
#include <math.h>

typedef __bf16 bf16x8 __attribute__((ext_vector_type(8)));
typedef float  f32x4  __attribute__((ext_vector_type(4)));
typedef unsigned short u16x4 __attribute__((ext_vector_type(4)));

#define BATCH  2
#define SEQ    2048
#define DMODEL 1024
#define NHEAD  16
#define DHEAD  64
#define MROWS  4096
#define N_QKV  3072
#define KDIM   1024
#define OUTSECT (MROWS*DMODEL)   // 4194304 elements

__device__ inline __bf16 f2bf(float f) {
    unsigned u = __builtin_bit_cast(unsigned, f);
    unsigned r = (u + 0x7fffu + ((u >> 16) & 1u)) >> 16;
    return __builtin_bit_cast(__bf16, (unsigned short)r);
}

// async global->LDS, 16B per lane; LDS dest is wave-uniform base + lane*16
__device__ inline void gload16(const void* g, void* l) {
    __builtin_amdgcn_global_load_lds(
        (const __attribute__((address_space(1))) void*)g,
        (__attribute__((address_space(3))) void*)l, 16, 0, 0);
}

// ---------------- conversion kernels (run once per launch) ----------------

__global__ __launch_bounds__(256) void cvt_x_k(const float* __restrict__ x,
                                               __bf16* __restrict__ xb) {
    size_t i = (size_t)blockIdx.x * 256 + threadIdx.x;
    const float4* p = (const float4*)x + i * 2;
    float4 a = p[0], b = p[1];
    __bf16 o[8] = {f2bf(a.x), f2bf(a.y), f2bf(a.z), f2bf(a.w),
                   f2bf(b.x), f2bf(b.y), f2bf(b.z), f2bf(b.w)};
    *(bf16x8*)(xb + i * 8) = *(bf16x8*)o;
}

// W [KDIM][Nw] f32 -> Wt [Nw][KDIM] bf16 (LDS-tiled transpose)
__global__ __launch_bounds__(256) void cvt_wt_k(const float* __restrict__ W,
                                                __bf16* __restrict__ Wt, int Nw) {
    __shared__ float t[64][65];
    const int k0 = blockIdx.y * 64, n0 = blockIdx.x * 64;
    const int tid = threadIdx.x;
    #pragma unroll
    for (int u = 0; u < 4; ++u) {
        int idx = u * 256 + tid;
        int r = idx >> 4, c4 = (idx & 15) << 2;
        float4 v = *(const float4*)&W[(size_t)(k0 + r) * Nw + n0 + c4];
        t[r][c4] = v.x; t[r][c4 + 1] = v.y; t[r][c4 + 2] = v.z; t[r][c4 + 3] = v.w;
    }
    __syncthreads();
    #pragma unroll
    for (int u = 0; u < 2; ++u) {
        int idx = u * 256 + tid;
        int n = idx >> 3, k8 = (idx & 7) << 3;
        __bf16 o[8];
        #pragma unroll
        for (int i = 0; i < 8; ++i) o[i] = f2bf(t[k8 + i][n]);
        *(bf16x8*)&Wt[(size_t)(n0 + n) * KDIM + k0 + k8] = *(bf16x8*)o;
    }
}

// ---------------- GEMM: A[M][1024] bf16 row-major, Bt[N][1024] bf16 row-major
template<int MODE, int FI, int FJ>
__global__ __launch_bounds__(256) void gemm_bf(
    const __bf16* __restrict__ A, const __bf16* __restrict__ Bt,
    const float* __restrict__ bias,
    float* __restrict__ fo, float* __restrict__ kf, float* __restrict__ vf,
    __bf16* __restrict__ qb, __bf16* __restrict__ kb, __bf16* __restrict__ vb,
    int nbx)
{
    constexpr int BMt = FI * 32, BNt = FJ * 32;
    __shared__ __align__(16) __bf16 As[BMt * 64];
    __shared__ __align__(16) __bf16 Bs[BNt * 64];

    const int tid = threadIdx.x, wid = tid >> 6, lane = tid & 63;
    const int l16 = lane & 15, lq = lane >> 4;
    const int wm = wid >> 1, wn = wid & 1;

    const int nwg = gridDim.x;
    const int bid = blockIdx.x;
    const int swz = (bid & 7) * (nwg >> 3) + (bid >> 3);
    const int m0 = (swz / nbx) * BMt;
    const int n0 = (swz % nbx) * BNt;

    const int lr8 = lane >> 3;
    const int colE = ((lane & 7) ^ lr8) << 3;

    f32x4 acc[FI][FJ];
    #pragma unroll
    for (int i = 0; i < FI; ++i)
        #pragma unroll
        for (int j = 0; j < FJ; ++j)
            acc[i][j] = f32x4{0.f, 0.f, 0.f, 0.f};

    for (int k0 = 0; k0 < KDIM; k0 += 64) {
        __syncthreads();
        #pragma unroll
        for (int c = wid; c < FI * 4 + FJ * 4; c += 4) {
            const bool isA = (c < FI * 4);
            const int ch = isA ? c : c - FI * 4;
            const int row = ch * 8 + lr8;
            const __bf16* src = isA ? (A  + (size_t)(m0 + row) * KDIM + k0 + colE)
                                    : (Bt + (size_t)(n0 + row) * KDIM + k0 + colE);
            gload16(src, (isA ? As : Bs) + ch * 512);
        }
        __syncthreads();
        #pragma unroll
        for (int kk = 0; kk < 2; ++kk) {
            bf16x8 af[FI], bfg[FJ];
            #pragma unroll
            for (int i = 0; i < FI; ++i) {
                int r = wm * (FI * 16) + i * 16 + l16;
                af[i] = *(const bf16x8*)&As[r * 64 + ((kk * 32 + lq * 8) ^ ((r & 7) << 3))];
            }
            #pragma unroll
            for (int j = 0; j < FJ; ++j) {
                int r = wn * (FJ * 16) + j * 16 + l16;
                bfg[j] = *(const bf16x8*)&Bs[r * 64 + ((kk * 32 + lq * 8) ^ ((r & 7) << 3))];
            }
            #pragma unroll
            for (int i = 0; i < FI; ++i)
                #pragma unroll
                for (int j = 0; j < FJ; ++j)
                    acc[i][j] = __builtin_amdgcn_mfma_f32_16x16x32_bf16(af[i], bfg[j], acc[i][j], 0, 0, 0);
        }
    }

    #pragma unroll
    for (int i = 0; i < FI; ++i) {
        #pragma unroll
        for (int j = 0; j < FJ; ++j) {
            const int col  = n0 + wn * (FJ * 16) + j * 16 + l16;
            const int rowb = m0 + wm * (FI * 16) + i * 16 + lq * 4;
            float v[4];
            #pragma unroll
            for (int r = 0; r < 4; ++r) v[r] = acc[i][j][r] + bias[col];
            if (MODE == 1) {
                #pragma unroll
                for (int r = 0; r < 4; ++r)
                    fo[(size_t)(rowb + r) * DMODEL + col] = v[r];
            } else {
                const int which = col >> 10, rem = col & 1023;
                const int h = rem >> 6, dh = rem & 63;
                const int bb = rowb >> 11, ll = rowb & 2047;
                const size_t lidx = ((size_t)(bb * NHEAD + h) * SEQ + ll) * DHEAD + dh;
                if (which == 0) {
                    #pragma unroll
                    for (int r = 0; r < 4; ++r) qb[lidx + (size_t)r * DHEAD] = f2bf(v[r]);
                } else if (which == 1) {
                    #pragma unroll
                    for (int r = 0; r < 4; ++r) {
                        kf[lidx + (size_t)r * DHEAD] = v[r];
                        kb[lidx + (size_t)r * DHEAD] = f2bf(v[r]);
                    }
                } else {
                    u16x4 pk;
                    #pragma unroll
                    for (int r = 0; r < 4; ++r) {
                        vf[lidx + (size_t)r * DHEAD] = v[r];
                        pk[r] = __builtin_bit_cast(unsigned short, f2bf(v[r]));
                    }
                    *(u16x4*)&vb[((size_t)(bb * NHEAD + h) * DHEAD + dh) * SEQ + ll] = pk;
                }
            }
        }
    }
}

// ---------------- flash attention: Qb,Kb [B,H,L,Dh] bf16, Vb [B,H,Dh,L] bf16
// Round 4: K/V double-buffered async prefetch (1 barrier/tile), LPT + XCD-bh map.
__global__ __launch_bounds__(256) void attn_k(
    const __bf16* __restrict__ Qb, const __bf16* __restrict__ Kb,
    const __bf16* __restrict__ Vb, __bf16* __restrict__ Ob)
{
    __shared__ __align__(16) __bf16 Qs[64 * 64];
    __shared__ __align__(16) __bf16 Ks[2][64 * 64];
    __shared__ __align__(16) __bf16 Vs[2][64 * 64];   // [dh][kv]
    __shared__ __align__(16) __bf16 Ps[4 * 16 * 64];

    const int tid = threadIdx.x, wid = tid >> 6, lane = tid & 63;
    const int l16 = lane & 15, lq = lane >> 4;

    // XCD x handles bh in {4x..4x+3} (2MB K/V -> L2-resident);
    // qt descends with launch index -> LPT (longest blocks first).
    const int bid = blockIdx.x;
    const int t   = bid >> 3;
    const int qt  = 31 - (t >> 2);
    const int bh  = (bid & 7) * 4 + (t & 3);
    const int h = bh & 15, bb = bh >> 4;
    const int q0 = qt * 64;
    const size_t kvbase = (size_t)bh * SEQ * DHEAD;
    const float slope = exp2f(-0.5f * (float)(h + 1));
    const int qr0 = wid * 16;
    const int lr8 = lane >> 3;
    const int colE = ((lane & 7) ^ lr8) << 3;

    // stage Q (8 chunks of 8 rows)
    #pragma unroll
    for (int u = 0; u < 2; ++u) {
        int ch = u * 4 + wid;
        int row = ch * 8 + lr8;
        gload16(Qb + kvbase + (size_t)(q0 + row) * DHEAD + colE, Qs + ch * 512);
    }
    // stage K/V tile 0 into buffer 0
    #pragma unroll
    for (int u = 0; u < 2; ++u) {
        int ch = u * 4 + wid;
        int row = ch * 8 + lr8;
        gload16(Kb + kvbase + (size_t)row * DHEAD + colE, Ks[0] + ch * 512);
        gload16(Vb + kvbase + (size_t)row * SEQ  + colE, Vs[0] + ch * 512);
    }
    __syncthreads();

    float mrow[4], lrow[4];
    f32x4 accO[4];
    #pragma unroll
    for (int r = 0; r < 4; ++r) { mrow[r] = -1e30f; lrow[r] = 0.f; }
    #pragma unroll
    for (int j = 0; j < 4; ++j) accO[j] = f32x4{0.f, 0.f, 0.f, 0.f};

    int cur = 0;
    for (int jt = 0; jt <= qt; ++jt) {
        const int j0 = jt * 64;

        // async prefetch next K/V tile into the other buffer (hidden under compute)
        if (jt < qt) {
            const int jn = j0 + 64;
            #pragma unroll
            for (int u = 0; u < 2; ++u) {
                int ch = u * 4 + wid;
                int row = ch * 8 + lr8;
                gload16(Kb + kvbase + (size_t)(jn + row) * DHEAD + colE, Ks[cur ^ 1] + ch * 512);
                gload16(Vb + kvbase + (size_t)row * SEQ + jn + colE,     Vs[cur ^ 1] + ch * 512);
            }
        }

        // S = Q K^T  (per wave: 16 q-rows x 64 kv-cols)
        f32x4 s[4];
        #pragma unroll
        for (int nf = 0; nf < 4; ++nf) s[nf] = f32x4{0.f, 0.f, 0.f, 0.f};
        const int qrow = qr0 + l16;
        bf16x8 aq0 = *(const bf16x8*)&Qs[qrow * 64 + ((lq * 8) ^ ((qrow & 7) << 3))];
        bf16x8 aq1 = *(const bf16x8*)&Qs[qrow * 64 + ((32 + lq * 8) ^ ((qrow & 7) << 3))];
        __builtin_amdgcn_s_setprio(1);
        #pragma unroll
        for (int nf = 0; nf < 4; ++nf) {
            int kr = nf * 16 + l16;
            bf16x8 bk0 = *(const bf16x8*)&Ks[cur][kr * 64 + ((lq * 8) ^ ((kr & 7) << 3))];
            bf16x8 bk1 = *(const bf16x8*)&Ks[cur][kr * 64 + ((32 + lq * 8) ^ ((kr & 7) << 3))];
            s[nf] = __builtin_amdgcn_mfma_f32_16x16x32_bf16(aq0, bk0, s[nf], 0, 0, 0);
            s[nf] = __builtin_amdgcn_mfma_f32_16x16x32_bf16(aq1, bk1, s[nf], 0, 0, 0);
        }
        __builtin_amdgcn_s_setprio(0);

        // bias + causal mask + online softmax
        #pragma unroll
        for (int r = 0; r < 4; ++r) {
            const int qi = q0 + qr0 + lq * 4 + r;
            float rm = -1e30f;
            #pragma unroll
            for (int nf = 0; nf < 4; ++nf) {
                int ki = j0 + nf * 16 + l16;
                float sc = s[nf][r] * 0.125f;
                sc = (ki <= qi) ? (sc + slope * (float)(ki - qi)) : -1e30f;
                s[nf][r] = sc;
                rm = fmaxf(rm, sc);
            }
            #pragma unroll
            for (int msk = 1; msk < 16; msk <<= 1)
                rm = fmaxf(rm, __shfl_xor(rm, msk));
            float mnew = fmaxf(mrow[r], rm);
            float rsum = 0.f;
            const int prow = lq * 4 + r;
            #pragma unroll
            for (int nf = 0; nf < 4; ++nf) {
                float p = __expf(s[nf][r] - mnew);
                Ps[wid * 1024 + prow * 64 + ((nf * 16 + l16) ^ ((prow & 7) << 3))] = f2bf(p);
                rsum += p;
            }
            #pragma unroll
            for (int msk = 1; msk < 16; msk <<= 1)
                rsum += __shfl_xor(rsum, msk);
            float scale = __expf(mrow[r] - mnew);
            lrow[r] = lrow[r] * scale + rsum;
            mrow[r] = mnew;
            #pragma unroll
            for (int nf = 0; nf < 4; ++nf) accO[nf][r] *= scale;
        }

        // O += P V
        bf16x8 ap0 = *(const bf16x8*)&Ps[wid * 1024 + l16 * 64 + ((lq * 8) ^ ((l16 & 7) << 3))];
        bf16x8 ap1 = *(const bf16x8*)&Ps[wid * 1024 + l16 * 64 + ((32 + lq * 8) ^ ((l16 & 7) << 3))];
        __builtin_amdgcn_s_setprio(1);
        #pragma unroll
        for (int nf = 0; nf < 4; ++nf) {
            int vr = nf * 16 + l16;
            bf16x8 bv0 = *(const bf16x8*)&Vs[cur][vr * 64 + ((lq * 8) ^ ((vr & 7) << 3))];
            bf16x8 bv1 = *(const bf16x8*)&Vs[cur][vr * 64 + ((32 + lq * 8) ^ ((vr & 7) << 3))];
            accO[nf] = __builtin_amdgcn_mfma_f32_16x16x32_bf16(ap0, bv0, accO[nf], 0, 0, 0);
            accO[nf] = __builtin_amdgcn_mfma_f32_16x16x32_bf16(ap1, bv1, accO[nf], 0, 0, 0);
        }
        __builtin_amdgcn_s_setprio(0);

        // single barrier per tile: drains prefetch (latency hidden under compute)
        __syncthreads();
        cur ^= 1;
    }

    #pragma unroll
    for (int nf = 0; nf < 4; ++nf) {
        #pragma unroll
        for (int r = 0; r < 4; ++r) {
            int qi = q0 + qr0 + lq * 4 + r;
            int dh = nf * 16 + l16;
            Ob[(size_t)(bb * SEQ + qi) * DMODEL + h * DHEAD + dh] = f2bf(accO[nf][r] / lrow[r]);
        }
    }
}

extern "C" void kernel_launch(void* const* d_in, const int* in_sizes, int n_in,
                              void* d_out, int out_size, void* d_ws, size_t ws_size,
                              hipStream_t stream) {
    const float* x     = (const float*)d_in[0];
    const float* W_in  = (const float*)d_in[1];
    const float* b_in  = (const float*)d_in[2];
    const float* W_out = (const float*)d_in[3];
    const float* b_out = (const float*)d_in[4];

    float* out = (float*)d_out;
    float* kf  = out + (size_t)OUTSECT;
    float* vf  = out + 2 * (size_t)OUTSECT;

    __bf16* qb = (__bf16*)d_out;                   // scratch in d_out sec 0
    __bf16* xb = (__bf16*)d_out + (size_t)OUTSECT;

    __bf16* ob  = (__bf16*)d_ws;                   // 8 MB
    __bf16* kb  = ob + (size_t)OUTSECT;            // 8 MB
    __bf16* vb  = kb + (size_t)OUTSECT;            // 8 MB [B,H,Dh,L]
    __bf16* wti = vb + (size_t)OUTSECT;            // 6 MB
    __bf16* wto = wti + (size_t)N_QKV * KDIM;      // 2 MB

    cvt_x_k <<<2048, 256, 0, stream>>>(x, xb);
    cvt_wt_k<<<dim3(48, 16), 256, 0, stream>>>(W_in,  wti, N_QKV);
    cvt_wt_k<<<dim3(16, 16), 256, 0, stream>>>(W_out, wto, DMODEL);

    gemm_bf<0, 4, 4><<<768, 256, 0, stream>>>(xb, wti, b_in,
        nullptr, kf, vf, qb, kb, vb, N_QKV / 128);

    attn_k<<<1024, 256, 0, stream>>>(qb, kb, vb, ob);

    gemm_bf<1, 2, 4><<<512, 256, 0, stream>>>(ob, wto, b_out,
        out, nullptr, nullptr, nullptr, nullptr, nullptr, DMODEL / 128);
}

// Round 5
// 203.917 us; speedup vs baseline: 2.7843x; 1.0916x over previous
//
#include <hip/hip_runtime.h>
#include <math.h>

typedef __bf16 bf16x8 __attribute__((ext_vector_type(8)));
typedef float  f32x4  __attribute__((ext_vector_type(4)));
typedef unsigned short u16x4 __attribute__((ext_vector_type(4)));

#define BATCH  2
#define SEQ    2048
#define DMODEL 1024
#define NHEAD  16
#define DHEAD  64
#define MROWS  4096
#define N_QKV  3072
#define KDIM   1024
#define OUTSECT (MROWS*DMODEL)   // 4194304 elements

#define LOG2E 1.44269504088896f
#define QSCALE (0.125f * LOG2E)  // folded into qb at GEMM1 epilogue

__device__ inline __bf16 f2bf(float f) {
    unsigned u = __builtin_bit_cast(unsigned, f);
    unsigned r = (u + 0x7fffu + ((u >> 16) & 1u)) >> 16;
    return __builtin_bit_cast(__bf16, (unsigned short)r);
}

// async global->LDS, 16B per lane; LDS dest is wave-uniform base + lane*16
__device__ inline void gload16(const void* g, void* l) {
    __builtin_amdgcn_global_load_lds(
        (const __attribute__((address_space(1))) void*)g,
        (__attribute__((address_space(3))) void*)l, 16, 0, 0);
}

// 16-lane (DPP row) reductions: ^1, ^2, ror:8(=^8), row_mirror (closes quads)
__device__ inline float dpp_max16(float x) {
    int v, t;
    v = __builtin_bit_cast(int, x);
    t = __builtin_amdgcn_update_dpp(v, v, 0xB1, 0xF, 0xF, false);   // quad_perm ^1
    x = fmaxf(x, __builtin_bit_cast(float, t));
    v = __builtin_bit_cast(int, x);
    t = __builtin_amdgcn_update_dpp(v, v, 0x4E, 0xF, 0xF, false);   // quad_perm ^2
    x = fmaxf(x, __builtin_bit_cast(float, t));
    v = __builtin_bit_cast(int, x);
    t = __builtin_amdgcn_update_dpp(v, v, 0x128, 0xF, 0xF, false);  // row_ror:8
    x = fmaxf(x, __builtin_bit_cast(float, t));
    v = __builtin_bit_cast(int, x);
    t = __builtin_amdgcn_update_dpp(v, v, 0x140, 0xF, 0xF, false);  // row_mirror
    x = fmaxf(x, __builtin_bit_cast(float, t));
    return x;
}
__device__ inline float dpp_sum16(float x) {
    int v, t;
    v = __builtin_bit_cast(int, x);
    t = __builtin_amdgcn_update_dpp(v, v, 0xB1, 0xF, 0xF, false);
    x += __builtin_bit_cast(float, t);
    v = __builtin_bit_cast(int, x);
    t = __builtin_amdgcn_update_dpp(v, v, 0x4E, 0xF, 0xF, false);
    x += __builtin_bit_cast(float, t);
    v = __builtin_bit_cast(int, x);
    t = __builtin_amdgcn_update_dpp(v, v, 0x128, 0xF, 0xF, false);
    x += __builtin_bit_cast(float, t);
    v = __builtin_bit_cast(int, x);
    t = __builtin_amdgcn_update_dpp(v, v, 0x140, 0xF, 0xF, false);
    x += __builtin_bit_cast(float, t);
    return x;
}

// ---------------- conversion kernels ----------------

__global__ __launch_bounds__(256) void cvt_x_k(const float* __restrict__ x,
                                               __bf16* __restrict__ xb) {
    size_t i = (size_t)blockIdx.x * 256 + threadIdx.x;
    const float4* p = (const float4*)x + i * 2;
    float4 a = p[0], b = p[1];
    __bf16 o[8] = {f2bf(a.x), f2bf(a.y), f2bf(a.z), f2bf(a.w),
                   f2bf(b.x), f2bf(b.y), f2bf(b.z), f2bf(b.w)};
    *(bf16x8*)(xb + i * 8) = *(bf16x8*)o;
}

__global__ __launch_bounds__(256) void cvt_wt_k(const float* __restrict__ W,
                                                __bf16* __restrict__ Wt, int Nw) {
    __shared__ float t[64][65];
    const int k0 = blockIdx.y * 64, n0 = blockIdx.x * 64;
    const int tid = threadIdx.x;
    #pragma unroll
    for (int u = 0; u < 4; ++u) {
        int idx = u * 256 + tid;
        int r = idx >> 4, c4 = (idx & 15) << 2;
        float4 v = *(const float4*)&W[(size_t)(k0 + r) * Nw + n0 + c4];
        t[r][c4] = v.x; t[r][c4 + 1] = v.y; t[r][c4 + 2] = v.z; t[r][c4 + 3] = v.w;
    }
    __syncthreads();
    #pragma unroll
    for (int u = 0; u < 2; ++u) {
        int idx = u * 256 + tid;
        int n = idx >> 3, k8 = (idx & 7) << 3;
        __bf16 o[8];
        #pragma unroll
        for (int i = 0; i < 8; ++i) o[i] = f2bf(t[k8 + i][n]);
        *(bf16x8*)&Wt[(size_t)(n0 + n) * KDIM + k0 + k8] = *(bf16x8*)o;
    }
}

// ---------------- GEMM: A[M][1024] bf16 row-major, Bt[N][1024] bf16 row-major
template<int MODE, int FI, int FJ>
__global__ __launch_bounds__(256) void gemm_bf(
    const __bf16* __restrict__ A, const __bf16* __restrict__ Bt,
    const float* __restrict__ bias,
    float* __restrict__ fo, float* __restrict__ kf, float* __restrict__ vf,
    __bf16* __restrict__ qb, __bf16* __restrict__ kb, __bf16* __restrict__ vb,
    int nbx)
{
    constexpr int BMt = FI * 32, BNt = FJ * 32;
    __shared__ __align__(16) __bf16 As[BMt * 64];
    __shared__ __align__(16) __bf16 Bs[BNt * 64];

    const int tid = threadIdx.x, wid = tid >> 6, lane = tid & 63;
    const int l16 = lane & 15, lq = lane >> 4;
    const int wm = wid >> 1, wn = wid & 1;

    const int nwg = gridDim.x;
    const int bid = blockIdx.x;
    const int swz = (bid & 7) * (nwg >> 3) + (bid >> 3);
    const int m0 = (swz / nbx) * BMt;
    const int n0 = (swz % nbx) * BNt;

    const int lr8 = lane >> 3;
    const int colE = ((lane & 7) ^ lr8) << 3;

    f32x4 acc[FI][FJ];
    #pragma unroll
    for (int i = 0; i < FI; ++i)
        #pragma unroll
        for (int j = 0; j < FJ; ++j)
            acc[i][j] = f32x4{0.f, 0.f, 0.f, 0.f};

    for (int k0 = 0; k0 < KDIM; k0 += 64) {
        __syncthreads();
        #pragma unroll
        for (int c = wid; c < FI * 4 + FJ * 4; c += 4) {
            const bool isA = (c < FI * 4);
            const int ch = isA ? c : c - FI * 4;
            const int row = ch * 8 + lr8;
            const __bf16* src = isA ? (A  + (size_t)(m0 + row) * KDIM + k0 + colE)
                                    : (Bt + (size_t)(n0 + row) * KDIM + k0 + colE);
            gload16(src, (isA ? As : Bs) + ch * 512);
        }
        __syncthreads();
        #pragma unroll
        for (int kk = 0; kk < 2; ++kk) {
            bf16x8 af[FI], bfg[FJ];
            #pragma unroll
            for (int i = 0; i < FI; ++i) {
                int r = wm * (FI * 16) + i * 16 + l16;
                af[i] = *(const bf16x8*)&As[r * 64 + ((kk * 32 + lq * 8) ^ ((r & 7) << 3))];
            }
            #pragma unroll
            for (int j = 0; j < FJ; ++j) {
                int r = wn * (FJ * 16) + j * 16 + l16;
                bfg[j] = *(const bf16x8*)&Bs[r * 64 + ((kk * 32 + lq * 8) ^ ((r & 7) << 3))];
            }
            #pragma unroll
            for (int i = 0; i < FI; ++i)
                #pragma unroll
                for (int j = 0; j < FJ; ++j)
                    acc[i][j] = __builtin_amdgcn_mfma_f32_16x16x32_bf16(af[i], bfg[j], acc[i][j], 0, 0, 0);
        }
    }

    #pragma unroll
    for (int i = 0; i < FI; ++i) {
        #pragma unroll
        for (int j = 0; j < FJ; ++j) {
            const int col  = n0 + wn * (FJ * 16) + j * 16 + l16;
            const int rowb = m0 + wm * (FI * 16) + i * 16 + lq * 4;
            float v[4];
            #pragma unroll
            for (int r = 0; r < 4; ++r) v[r] = acc[i][j][r] + bias[col];
            if (MODE == 1) {
                #pragma unroll
                for (int r = 0; r < 4; ++r)
                    fo[(size_t)(rowb + r) * DMODEL + col] = v[r];
            } else {
                const int which = col >> 10, rem = col & 1023;
                const int h = rem >> 6, dh = rem & 63;
                const int bb = rowb >> 11, ll = rowb & 2047;
                const size_t lidx = ((size_t)(bb * NHEAD + h) * SEQ + ll) * DHEAD + dh;
                if (which == 0) {
                    // fold softmax scale (0.125*log2e) into q
                    #pragma unroll
                    for (int r = 0; r < 4; ++r)
                        qb[lidx + (size_t)r * DHEAD] = f2bf(v[r] * QSCALE);
                } else if (which == 1) {
                    #pragma unroll
                    for (int r = 0; r < 4; ++r) {
                        kf[lidx + (size_t)r * DHEAD] = v[r];
                        kb[lidx + (size_t)r * DHEAD] = f2bf(v[r]);
                    }
                } else {
                    u16x4 pk;
                    #pragma unroll
                    for (int r = 0; r < 4; ++r) {
                        vf[lidx + (size_t)r * DHEAD] = v[r];
                        pk[r] = __builtin_bit_cast(unsigned short, f2bf(v[r]));
                    }
                    *(u16x4*)&vb[((size_t)(bb * NHEAD + h) * DHEAD + dh) * SEQ + ll] = pk;
                }
            }
        }
    }
}

// ---------------- flash attention (round 5: log2-domain, bias-in-acc, DPP softmax)
// Qb pre-scaled by 0.125*log2e; Kb [B,H,L,Dh]; Vb [B,H,Dh,L] bf16.
__global__ __launch_bounds__(256) void attn_k(
    const __bf16* __restrict__ Qb, const __bf16* __restrict__ Kb,
    const __bf16* __restrict__ Vb, __bf16* __restrict__ Ob)
{
    __shared__ __align__(16) __bf16 Qs[64 * 64];
    __shared__ __align__(16) __bf16 Ks[2][64 * 64];
    __shared__ __align__(16) __bf16 Vs[2][64 * 64];   // [dh][kv]
    __shared__ __align__(16) __bf16 Ps[4 * 16 * 64];

    const int tid = threadIdx.x, wid = tid >> 6, lane = tid & 63;
    const int l16 = lane & 15, lq = lane >> 4;

    const int bid = blockIdx.x;
    const int t   = bid >> 3;
    const int qt  = 31 - (t >> 2);
    const int bh  = (bid & 7) * 4 + (t & 3);
    const int h = bh & 15, bb = bh >> 4;
    const int q0 = qt * 64;
    const size_t kvbase = (size_t)bh * SEQ * DHEAD;
    const float slope2 = exp2f(-0.5f * (float)(h + 1)) * LOG2E;  // log2-domain slope
    const int qr0 = wid * 16;
    const int lr8 = lane >> 3;
    const int colE = ((lane & 7) ^ lr8) << 3;

    // stage Q
    #pragma unroll
    for (int u = 0; u < 2; ++u) {
        int ch = u * 4 + wid;
        int row = ch * 8 + lr8;
        gload16(Qb + kvbase + (size_t)(q0 + row) * DHEAD + colE, Qs + ch * 512);
    }
    // stage K/V tile 0
    #pragma unroll
    for (int u = 0; u < 2; ++u) {
        int ch = u * 4 + wid;
        int row = ch * 8 + lr8;
        gload16(Kb + kvbase + (size_t)row * DHEAD + colE, Ks[0] + ch * 512);
        gload16(Vb + kvbase + (size_t)row * SEQ  + colE, Vs[0] + ch * 512);
    }
    __syncthreads();

    // running ALiBi bias per (r,nf): ct = slope2*((j0 + nf*16 + l16) - qi), j0=0
    // advanced by dtj = slope2*64 each k-tile; used as the QK accumulator init.
    float ct[4][4];
    #pragma unroll
    for (int r = 0; r < 4; ++r) {
        const int qi = q0 + qr0 + lq * 4 + r;
        #pragma unroll
        for (int nf = 0; nf < 4; ++nf)
            ct[r][nf] = slope2 * (float)(nf * 16 + l16 - qi);
    }
    const float dtj = slope2 * 64.f;

    float mrow[4], lrow[4];
    f32x4 accO[4];
    #pragma unroll
    for (int r = 0; r < 4; ++r) { mrow[r] = -1e30f; lrow[r] = 0.f; }
    #pragma unroll
    for (int j = 0; j < 4; ++j) accO[j] = f32x4{0.f, 0.f, 0.f, 0.f};

    int cur = 0;
    for (int jt = 0; jt <= qt; ++jt) {
        // async prefetch next K/V tile
        if (jt < qt) {
            const int jn = (jt + 1) * 64;
            #pragma unroll
            for (int u = 0; u < 2; ++u) {
                int ch = u * 4 + wid;
                int row = ch * 8 + lr8;
                gload16(Kb + kvbase + (size_t)(jn + row) * DHEAD + colE, Ks[cur ^ 1] + ch * 512);
                gload16(Vb + kvbase + (size_t)row * SEQ + jn + colE,     Vs[cur ^ 1] + ch * 512);
            }
        }

        // QK^T accumulator initialized with ALiBi bias (log2 domain)
        f32x4 s[4];
        #pragma unroll
        for (int nf = 0; nf < 4; ++nf) {
            #pragma unroll
            for (int r = 0; r < 4; ++r) s[nf][r] = ct[r][nf];
        }
        if (jt == qt) {
            // diagonal tile: kill masked positions (tile-invariant pattern)
            #pragma unroll
            for (int nf = 0; nf < 4; ++nf)
                #pragma unroll
                for (int r = 0; r < 4; ++r)
                    if (nf * 16 + l16 > qr0 + lq * 4 + r) s[nf][r] = -3e38f;
        }

        const int qrow = qr0 + l16;
        bf16x8 aq0 = *(const bf16x8*)&Qs[qrow * 64 + ((lq * 8) ^ ((qrow & 7) << 3))];
        bf16x8 aq1 = *(const bf16x8*)&Qs[qrow * 64 + ((32 + lq * 8) ^ ((qrow & 7) << 3))];
        __builtin_amdgcn_s_setprio(1);
        #pragma unroll
        for (int nf = 0; nf < 4; ++nf) {
            int kr = nf * 16 + l16;
            bf16x8 bk0 = *(const bf16x8*)&Ks[cur][kr * 64 + ((lq * 8) ^ ((kr & 7) << 3))];
            bf16x8 bk1 = *(const bf16x8*)&Ks[cur][kr * 64 + ((32 + lq * 8) ^ ((kr & 7) << 3))];
            s[nf] = __builtin_amdgcn_mfma_f32_16x16x32_bf16(aq0, bk0, s[nf], 0, 0, 0);
            s[nf] = __builtin_amdgcn_mfma_f32_16x16x32_bf16(aq1, bk1, s[nf], 0, 0, 0);
        }
        __builtin_amdgcn_s_setprio(0);

        // online softmax, log2 domain, DPP reductions
        #pragma unroll
        for (int r = 0; r < 4; ++r) {
            float rm = fmaxf(fmaxf(s[0][r], s[1][r]), fmaxf(s[2][r], s[3][r]));
            rm = dpp_max16(rm);
            float mnew = fmaxf(mrow[r], rm);
            float p0 = __builtin_amdgcn_exp2f(s[0][r] - mnew);
            float p1 = __builtin_amdgcn_exp2f(s[1][r] - mnew);
            float p2 = __builtin_amdgcn_exp2f(s[2][r] - mnew);
            float p3 = __builtin_amdgcn_exp2f(s[3][r] - mnew);
            const int prow = lq * 4 + r;
            const int pb = wid * 1024 + prow * 64;
            const int px = (prow & 7) << 3;
            Ps[pb + ((l16     ) ^ px)] = (__bf16)p0;
            Ps[pb + ((l16 + 16) ^ px)] = (__bf16)p1;
            Ps[pb + ((l16 + 32) ^ px)] = (__bf16)p2;
            Ps[pb + ((l16 + 48) ^ px)] = (__bf16)p3;
            float rsum = dpp_sum16((p0 + p1) + (p2 + p3));
            float scale = __builtin_amdgcn_exp2f(mrow[r] - mnew);
            lrow[r] = lrow[r] * scale + rsum;
            mrow[r] = mnew;
            #pragma unroll
            for (int nf = 0; nf < 4; ++nf) accO[nf][r] *= scale;
        }
        #pragma unroll
        for (int r = 0; r < 4; ++r)
            #pragma unroll
            for (int nf = 0; nf < 4; ++nf) ct[r][nf] += dtj;

        // O += P V
        bf16x8 ap0 = *(const bf16x8*)&Ps[wid * 1024 + l16 * 64 + ((lq * 8) ^ ((l16 & 7) << 3))];
        bf16x8 ap1 = *(const bf16x8*)&Ps[wid * 1024 + l16 * 64 + ((32 + lq * 8) ^ ((l16 & 7) << 3))];
        __builtin_amdgcn_s_setprio(1);
        #pragma unroll
        for (int nf = 0; nf < 4; ++nf) {
            int vr = nf * 16 + l16;
            bf16x8 bv0 = *(const bf16x8*)&Vs[cur][vr * 64 + ((lq * 8) ^ ((vr & 7) << 3))];
            bf16x8 bv1 = *(const bf16x8*)&Vs[cur][vr * 64 + ((32 + lq * 8) ^ ((vr & 7) << 3))];
            accO[nf] = __builtin_amdgcn_mfma_f32_16x16x32_bf16(ap0, bv0, accO[nf], 0, 0, 0);
            accO[nf] = __builtin_amdgcn_mfma_f32_16x16x32_bf16(ap1, bv1, accO[nf], 0, 0, 0);
        }
        __builtin_amdgcn_s_setprio(0);

        __syncthreads();
        cur ^= 1;
    }

    #pragma unroll
    for (int r = 0; r < 4; ++r) {
        const float inv = __builtin_amdgcn_rcpf(lrow[r]);
        const int qi = q0 + qr0 + lq * 4 + r;
        #pragma unroll
        for (int nf = 0; nf < 4; ++nf) {
            int dh = nf * 16 + l16;
            Ob[(size_t)(bb * SEQ + qi) * DMODEL + h * DHEAD + dh] = (__bf16)(accO[nf][r] * inv);
        }
    }
}

extern "C" void kernel_launch(void* const* d_in, const int* in_sizes, int n_in,
                              void* d_out, int out_size, void* d_ws, size_t ws_size,
                              hipStream_t stream) {
    const float* x     = (const float*)d_in[0];
    const float* W_in  = (const float*)d_in[1];
    const float* b_in  = (const float*)d_in[2];
    const float* W_out = (const float*)d_in[3];
    const float* b_out = (const float*)d_in[4];

    float* out = (float*)d_out;
    float* kf  = out + (size_t)OUTSECT;
    float* vf  = out + 2 * (size_t)OUTSECT;

    __bf16* qb = (__bf16*)d_out;                   // scratch in d_out sec 0
    __bf16* xb = (__bf16*)d_out + (size_t)OUTSECT;

    __bf16* ob  = (__bf16*)d_ws;                   // 8 MB
    __bf16* kb  = ob + (size_t)OUTSECT;            // 8 MB
    __bf16* vb  = kb + (size_t)OUTSECT;            // 8 MB [B,H,Dh,L]
    __bf16* wti = vb + (size_t)OUTSECT;            // 6 MB
    __bf16* wto = wti + (size_t)N_QKV * KDIM;      // 2 MB

    cvt_x_k <<<2048, 256, 0, stream>>>(x, xb);
    cvt_wt_k<<<dim3(48, 16), 256, 0, stream>>>(W_in,  wti, N_QKV);
    cvt_wt_k<<<dim3(16, 16), 256, 0, stream>>>(W_out, wto, DMODEL);

    gemm_bf<0, 4, 4><<<768, 256, 0, stream>>>(xb, wti, b_in,
        nullptr, kf, vf, qb, kb, vb, N_QKV / 128);

    attn_k<<<1024, 256, 0, stream>>>(qb, kb, vb, ob);

    gemm_bf<1, 2, 4><<<512, 256, 0, stream>>>(ob, wto, b_out,
        out, nullptr, nullptr, nullptr, nullptr, nullptr, DMODEL / 128);
}

// Round 6
// 199.892 us; speedup vs baseline: 2.8404x; 1.0201x over previous
//
#include <hip/hip_runtime.h>
#include <math.h>

typedef __bf16 bf16x8 __attribute__((ext_vector_type(8)));
typedef float  f32x4  __attribute__((ext_vector_type(4)));
typedef unsigned short u16x4 __attribute__((ext_vector_type(4)));

#define BATCH  2
#define SEQ    2048
#define DMODEL 1024
#define NHEAD  16
#define DHEAD  64
#define MROWS  4096
#define N_QKV  3072
#define KDIM   1024
#define OUTSECT (MROWS*DMODEL)   // 4194304 elements

#define LOG2E 1.44269504088896f
#define QSCALE (0.125f * LOG2E)  // folded into qb at GEMM1 epilogue

__device__ inline __bf16 f2bf(float f) {
    unsigned u = __builtin_bit_cast(unsigned, f);
    unsigned r = (u + 0x7fffu + ((u >> 16) & 1u)) >> 16;
    return __builtin_bit_cast(__bf16, (unsigned short)r);
}

// async global->LDS, 16B per lane; LDS dest is wave-uniform base + lane*16
__device__ inline void gload16(const void* g, void* l) {
    __builtin_amdgcn_global_load_lds(
        (const __attribute__((address_space(1))) void*)g,
        (__attribute__((address_space(3))) void*)l, 16, 0, 0);
}

// 16-lane (DPP row) reductions: ^1, ^2, ror:8(=^8), row_mirror (closes quads)
__device__ inline float dpp_max16(float x) {
    int v, t;
    v = __builtin_bit_cast(int, x);
    t = __builtin_amdgcn_update_dpp(v, v, 0xB1, 0xF, 0xF, false);   // quad_perm ^1
    x = fmaxf(x, __builtin_bit_cast(float, t));
    v = __builtin_bit_cast(int, x);
    t = __builtin_amdgcn_update_dpp(v, v, 0x4E, 0xF, 0xF, false);   // quad_perm ^2
    x = fmaxf(x, __builtin_bit_cast(float, t));
    v = __builtin_bit_cast(int, x);
    t = __builtin_amdgcn_update_dpp(v, v, 0x128, 0xF, 0xF, false);  // row_ror:8
    x = fmaxf(x, __builtin_bit_cast(float, t));
    v = __builtin_bit_cast(int, x);
    t = __builtin_amdgcn_update_dpp(v, v, 0x140, 0xF, 0xF, false);  // row_mirror
    x = fmaxf(x, __builtin_bit_cast(float, t));
    return x;
}
__device__ inline float dpp_sum16(float x) {
    int v, t;
    v = __builtin_bit_cast(int, x);
    t = __builtin_amdgcn_update_dpp(v, v, 0xB1, 0xF, 0xF, false);
    x += __builtin_bit_cast(float, t);
    v = __builtin_bit_cast(int, x);
    t = __builtin_amdgcn_update_dpp(v, v, 0x4E, 0xF, 0xF, false);
    x += __builtin_bit_cast(float, t);
    v = __builtin_bit_cast(int, x);
    t = __builtin_amdgcn_update_dpp(v, v, 0x128, 0xF, 0xF, false);
    x += __builtin_bit_cast(float, t);
    v = __builtin_bit_cast(int, x);
    t = __builtin_amdgcn_update_dpp(v, v, 0x140, 0xF, 0xF, false);
    x += __builtin_bit_cast(float, t);
    return x;
}

// ---------------- fused conversion kernel (1 launch) ----------------
// blocks [0,2048): x f32->bf16 copy; [2048,2816): W_in transpose; [2816,3072): W_out transpose
__global__ __launch_bounds__(256) void cvt_all_k(
    const float* __restrict__ x, __bf16* __restrict__ xb,
    const float* __restrict__ W_in, __bf16* __restrict__ wti,
    const float* __restrict__ W_out, __bf16* __restrict__ wto)
{
    __shared__ float t[64][65];
    const int b = blockIdx.x;
    const int tid = threadIdx.x;
    if (b < 2048) {
        size_t i = (size_t)b * 256 + tid;
        const float4* p = (const float4*)x + i * 2;
        float4 a = p[0], c = p[1];
        __bf16 o[8] = {f2bf(a.x), f2bf(a.y), f2bf(a.z), f2bf(a.w),
                       f2bf(c.x), f2bf(c.y), f2bf(c.z), f2bf(c.w)};
        *(bf16x8*)(xb + i * 8) = *(bf16x8*)o;
        return;
    }
    const float* W;  __bf16* Wt;  int Nw, bx, by;
    if (b < 2816) { int c = b - 2048; W = W_in;  Wt = wti; Nw = N_QKV;  bx = c % 48; by = c / 48; }
    else          { int c = b - 2816; W = W_out; Wt = wto; Nw = DMODEL; bx = c % 16; by = c / 16; }
    const int k0 = by * 64, n0 = bx * 64;
    #pragma unroll
    for (int u = 0; u < 4; ++u) {
        int idx = u * 256 + tid;
        int r = idx >> 4, c4 = (idx & 15) << 2;
        float4 v = *(const float4*)&W[(size_t)(k0 + r) * Nw + n0 + c4];
        t[r][c4] = v.x; t[r][c4 + 1] = v.y; t[r][c4 + 2] = v.z; t[r][c4 + 3] = v.w;
    }
    __syncthreads();
    #pragma unroll
    for (int u = 0; u < 2; ++u) {
        int idx = u * 256 + tid;
        int n = idx >> 3, k8 = (idx & 7) << 3;
        __bf16 o[8];
        #pragma unroll
        for (int i = 0; i < 8; ++i) o[i] = f2bf(t[k8 + i][n]);
        *(bf16x8*)&Wt[(size_t)(n0 + n) * KDIM + k0 + k8] = *(bf16x8*)o;
    }
}

// ---------------- GEMM: A[M][1024] bf16 row-major, Bt[N][1024] bf16 row-major
template<int MODE, int FI, int FJ>
__global__ __launch_bounds__(256) void gemm_bf(
    const __bf16* __restrict__ A, const __bf16* __restrict__ Bt,
    const float* __restrict__ bias,
    float* __restrict__ fo, float* __restrict__ kf, float* __restrict__ vf,
    __bf16* __restrict__ qb, __bf16* __restrict__ kb, __bf16* __restrict__ vb,
    int nbx)
{
    constexpr int BMt = FI * 32, BNt = FJ * 32;
    __shared__ __align__(16) __bf16 As[BMt * 64];
    __shared__ __align__(16) __bf16 Bs[BNt * 64];

    const int tid = threadIdx.x, wid = tid >> 6, lane = tid & 63;
    const int l16 = lane & 15, lq = lane >> 4;
    const int wm = wid >> 1, wn = wid & 1;

    const int nwg = gridDim.x;
    const int bid = blockIdx.x;
    const int swz = (bid & 7) * (nwg >> 3) + (bid >> 3);
    const int m0 = (swz / nbx) * BMt;
    const int n0 = (swz % nbx) * BNt;

    const int lr8 = lane >> 3;
    const int colE = ((lane & 7) ^ lr8) << 3;

    f32x4 acc[FI][FJ];
    #pragma unroll
    for (int i = 0; i < FI; ++i)
        #pragma unroll
        for (int j = 0; j < FJ; ++j)
            acc[i][j] = f32x4{0.f, 0.f, 0.f, 0.f};

    for (int k0 = 0; k0 < KDIM; k0 += 64) {
        __syncthreads();
        #pragma unroll
        for (int c = wid; c < FI * 4 + FJ * 4; c += 4) {
            const bool isA = (c < FI * 4);
            const int ch = isA ? c : c - FI * 4;
            const int row = ch * 8 + lr8;
            const __bf16* src = isA ? (A  + (size_t)(m0 + row) * KDIM + k0 + colE)
                                    : (Bt + (size_t)(n0 + row) * KDIM + k0 + colE);
            gload16(src, (isA ? As : Bs) + ch * 512);
        }
        __syncthreads();
        #pragma unroll
        for (int kk = 0; kk < 2; ++kk) {
            bf16x8 af[FI], bfg[FJ];
            #pragma unroll
            for (int i = 0; i < FI; ++i) {
                int r = wm * (FI * 16) + i * 16 + l16;
                af[i] = *(const bf16x8*)&As[r * 64 + ((kk * 32 + lq * 8) ^ ((r & 7) << 3))];
            }
            #pragma unroll
            for (int j = 0; j < FJ; ++j) {
                int r = wn * (FJ * 16) + j * 16 + l16;
                bfg[j] = *(const bf16x8*)&Bs[r * 64 + ((kk * 32 + lq * 8) ^ ((r & 7) << 3))];
            }
            #pragma unroll
            for (int i = 0; i < FI; ++i)
                #pragma unroll
                for (int j = 0; j < FJ; ++j)
                    acc[i][j] = __builtin_amdgcn_mfma_f32_16x16x32_bf16(af[i], bfg[j], acc[i][j], 0, 0, 0);
        }
    }

    #pragma unroll
    for (int i = 0; i < FI; ++i) {
        #pragma unroll
        for (int j = 0; j < FJ; ++j) {
            const int col  = n0 + wn * (FJ * 16) + j * 16 + l16;
            const int rowb = m0 + wm * (FI * 16) + i * 16 + lq * 4;
            float v[4];
            #pragma unroll
            for (int r = 0; r < 4; ++r) v[r] = acc[i][j][r] + bias[col];
            if (MODE == 1) {
                #pragma unroll
                for (int r = 0; r < 4; ++r)
                    fo[(size_t)(rowb + r) * DMODEL + col] = v[r];
            } else {
                const int which = col >> 10, rem = col & 1023;
                const int h = rem >> 6, dh = rem & 63;
                const int bb = rowb >> 11, ll = rowb & 2047;
                const size_t lidx = ((size_t)(bb * NHEAD + h) * SEQ + ll) * DHEAD + dh;
                if (which == 0) {
                    // fold softmax scale (0.125*log2e) into q
                    #pragma unroll
                    for (int r = 0; r < 4; ++r)
                        qb[lidx + (size_t)r * DHEAD] = f2bf(v[r] * QSCALE);
                } else if (which == 1) {
                    #pragma unroll
                    for (int r = 0; r < 4; ++r) {
                        kf[lidx + (size_t)r * DHEAD] = v[r];
                        kb[lidx + (size_t)r * DHEAD] = f2bf(v[r]);
                    }
                } else {
                    u16x4 pk;
                    #pragma unroll
                    for (int r = 0; r < 4; ++r) {
                        vf[lidx + (size_t)r * DHEAD] = v[r];
                        pk[r] = __builtin_bit_cast(unsigned short, f2bf(v[r]));
                    }
                    *(u16x4*)&vb[((size_t)(bb * NHEAD + h) * DHEAD + dh) * SEQ + ll] = pk;
                }
            }
        }
    }
}

// ---------------- flash attention (round 6: + defer-max T13, fma s-init)
// Qb pre-scaled by 0.125*log2e; Kb [B,H,L,Dh]; Vb [B,H,Dh,L] bf16.
__global__ __launch_bounds__(256) void attn_k(
    const __bf16* __restrict__ Qb, const __bf16* __restrict__ Kb,
    const __bf16* __restrict__ Vb, __bf16* __restrict__ Ob)
{
    __shared__ __align__(16) __bf16 Qs[64 * 64];
    __shared__ __align__(16) __bf16 Ks[2][64 * 64];
    __shared__ __align__(16) __bf16 Vs[2][64 * 64];   // [dh][kv]
    __shared__ __align__(16) __bf16 Ps[4 * 16 * 64];

    const int tid = threadIdx.x, wid = tid >> 6, lane = tid & 63;
    const int l16 = lane & 15, lq = lane >> 4;

    const int bid = blockIdx.x;
    const int t   = bid >> 3;
    const int qt  = 31 - (t >> 2);
    const int bh  = (bid & 7) * 4 + (t & 3);
    const int h = bh & 15, bb = bh >> 4;
    const int q0 = qt * 64;
    const size_t kvbase = (size_t)bh * SEQ * DHEAD;
    const float slope2 = exp2f(-0.5f * (float)(h + 1)) * LOG2E;  // log2-domain slope
    const int qr0 = wid * 16;
    const int lr8 = lane >> 3;
    const int colE = ((lane & 7) ^ lr8) << 3;

    // stage Q
    #pragma unroll
    for (int u = 0; u < 2; ++u) {
        int ch = u * 4 + wid;
        int row = ch * 8 + lr8;
        gload16(Qb + kvbase + (size_t)(q0 + row) * DHEAD + colE, Qs + ch * 512);
    }
    // stage K/V tile 0
    #pragma unroll
    for (int u = 0; u < 2; ++u) {
        int ch = u * 4 + wid;
        int row = ch * 8 + lr8;
        gload16(Kb + kvbase + (size_t)row * DHEAD + colE, Ks[0] + ch * 512);
        gload16(Vb + kvbase + (size_t)row * SEQ  + colE, Vs[0] + ch * 512);
    }
    __syncthreads();

    // base ALiBi bias (jt=0): ct = slope2*((nf*16+l16) - qi); per-tile s = ct + jt*dtj
    float ct[4][4];
    #pragma unroll
    for (int r = 0; r < 4; ++r) {
        const int qi = q0 + qr0 + lq * 4 + r;
        #pragma unroll
        for (int nf = 0; nf < 4; ++nf)
            ct[r][nf] = slope2 * (float)(nf * 16 + l16 - qi);
    }
    const float dtj = slope2 * 64.f;

    float mrow[4], lrow[4];
    f32x4 accO[4];
    #pragma unroll
    for (int r = 0; r < 4; ++r) { mrow[r] = -1e30f; lrow[r] = 0.f; }
    #pragma unroll
    for (int j = 0; j < 4; ++j) accO[j] = f32x4{0.f, 0.f, 0.f, 0.f};

    int cur = 0;
    for (int jt = 0; jt <= qt; ++jt) {
        // async prefetch next K/V tile
        if (jt < qt) {
            const int jn = (jt + 1) * 64;
            #pragma unroll
            for (int u = 0; u < 2; ++u) {
                int ch = u * 4 + wid;
                int row = ch * 8 + lr8;
                gload16(Kb + kvbase + (size_t)(jn + row) * DHEAD + colE, Ks[cur ^ 1] + ch * 512);
                gload16(Vb + kvbase + (size_t)row * SEQ + jn + colE,     Vs[cur ^ 1] + ch * 512);
            }
        }

        // QK^T accumulator initialized with ALiBi bias (log2 domain)
        const float tb = dtj * (float)jt;
        f32x4 s[4];
        #pragma unroll
        for (int nf = 0; nf < 4; ++nf) {
            #pragma unroll
            for (int r = 0; r < 4; ++r) s[nf][r] = ct[r][nf] + tb;
        }
        if (jt == qt) {
            // diagonal tile: kill masked positions (tile-invariant pattern)
            #pragma unroll
            for (int nf = 0; nf < 4; ++nf)
                #pragma unroll
                for (int r = 0; r < 4; ++r)
                    if (nf * 16 + l16 > qr0 + lq * 4 + r) s[nf][r] = -3e38f;
        }

        const int qrow = qr0 + l16;
        bf16x8 aq0 = *(const bf16x8*)&Qs[qrow * 64 + ((lq * 8) ^ ((qrow & 7) << 3))];
        bf16x8 aq1 = *(const bf16x8*)&Qs[qrow * 64 + ((32 + lq * 8) ^ ((qrow & 7) << 3))];
        __builtin_amdgcn_s_setprio(1);
        #pragma unroll
        for (int nf = 0; nf < 4; ++nf) {
            int kr = nf * 16 + l16;
            bf16x8 bk0 = *(const bf16x8*)&Ks[cur][kr * 64 + ((lq * 8) ^ ((kr & 7) << 3))];
            bf16x8 bk1 = *(const bf16x8*)&Ks[cur][kr * 64 + ((32 + lq * 8) ^ ((kr & 7) << 3))];
            s[nf] = __builtin_amdgcn_mfma_f32_16x16x32_bf16(aq0, bk0, s[nf], 0, 0, 0);
            s[nf] = __builtin_amdgcn_mfma_f32_16x16x32_bf16(aq1, bk1, s[nf], 0, 0, 0);
        }
        __builtin_amdgcn_s_setprio(0);

        // online softmax, log2 domain, DPP reductions, defer-max (THR=8)
        float rm[4];
        #pragma unroll
        for (int r = 0; r < 4; ++r)
            rm[r] = dpp_max16(fmaxf(fmaxf(s[0][r], s[1][r]), fmaxf(s[2][r], s[3][r])));
        bool need = (rm[0] > mrow[0] + 8.f) || (rm[1] > mrow[1] + 8.f) ||
                    (rm[2] > mrow[2] + 8.f) || (rm[3] > mrow[3] + 8.f);
        if (__any(need)) {
            #pragma unroll
            for (int r = 0; r < 4; ++r) {
                float mnew = fmaxf(mrow[r], rm[r]);
                float scale = __builtin_amdgcn_exp2f(mrow[r] - mnew);
                lrow[r] *= scale;
                mrow[r] = mnew;
                #pragma unroll
                for (int nf = 0; nf < 4; ++nf) accO[nf][r] *= scale;
            }
        }
        #pragma unroll
        for (int r = 0; r < 4; ++r) {
            float p0 = __builtin_amdgcn_exp2f(s[0][r] - mrow[r]);
            float p1 = __builtin_amdgcn_exp2f(s[1][r] - mrow[r]);
            float p2 = __builtin_amdgcn_exp2f(s[2][r] - mrow[r]);
            float p3 = __builtin_amdgcn_exp2f(s[3][r] - mrow[r]);
            const int prow = lq * 4 + r;
            const int pb = wid * 1024 + prow * 64;
            const int px = (prow & 7) << 3;
            Ps[pb + ((l16     ) ^ px)] = (__bf16)p0;
            Ps[pb + ((l16 + 16) ^ px)] = (__bf16)p1;
            Ps[pb + ((l16 + 32) ^ px)] = (__bf16)p2;
            Ps[pb + ((l16 + 48) ^ px)] = (__bf16)p3;
            lrow[r] += dpp_sum16((p0 + p1) + (p2 + p3));
        }

        // O += P V
        bf16x8 ap0 = *(const bf16x8*)&Ps[wid * 1024 + l16 * 64 + ((lq * 8) ^ ((l16 & 7) << 3))];
        bf16x8 ap1 = *(const bf16x8*)&Ps[wid * 1024 + l16 * 64 + ((32 + lq * 8) ^ ((l16 & 7) << 3))];
        __builtin_amdgcn_s_setprio(1);
        #pragma unroll
        for (int nf = 0; nf < 4; ++nf) {
            int vr = nf * 16 + l16;
            bf16x8 bv0 = *(const bf16x8*)&Vs[cur][vr * 64 + ((lq * 8) ^ ((vr & 7) << 3))];
            bf16x8 bv1 = *(const bf16x8*)&Vs[cur][vr * 64 + ((32 + lq * 8) ^ ((vr & 7) << 3))];
            accO[nf] = __builtin_amdgcn_mfma_f32_16x16x32_bf16(ap0, bv0, accO[nf], 0, 0, 0);
            accO[nf] = __builtin_amdgcn_mfma_f32_16x16x32_bf16(ap1, bv1, accO[nf], 0, 0, 0);
        }
        __builtin_amdgcn_s_setprio(0);

        __syncthreads();
        cur ^= 1;
    }

    #pragma unroll
    for (int r = 0; r < 4; ++r) {
        const float inv = __builtin_amdgcn_rcpf(lrow[r]);
        const int qi = q0 + qr0 + lq * 4 + r;
        #pragma unroll
        for (int nf = 0; nf < 4; ++nf) {
            int dh = nf * 16 + l16;
            Ob[(size_t)(bb * SEQ + qi) * DMODEL + h * DHEAD + dh] = (__bf16)(accO[nf][r] * inv);
        }
    }
}

extern "C" void kernel_launch(void* const* d_in, const int* in_sizes, int n_in,
                              void* d_out, int out_size, void* d_ws, size_t ws_size,
                              hipStream_t stream) {
    const float* x     = (const float*)d_in[0];
    const float* W_in  = (const float*)d_in[1];
    const float* b_in  = (const float*)d_in[2];
    const float* W_out = (const float*)d_in[3];
    const float* b_out = (const float*)d_in[4];

    float* out = (float*)d_out;
    float* kf  = out + (size_t)OUTSECT;
    float* vf  = out + 2 * (size_t)OUTSECT;

    __bf16* qb = (__bf16*)d_out;                   // scratch in d_out sec 0
    __bf16* xb = (__bf16*)d_out + (size_t)OUTSECT;

    __bf16* ob  = (__bf16*)d_ws;                   // 8 MB
    __bf16* kb  = ob + (size_t)OUTSECT;            // 8 MB
    __bf16* vb  = kb + (size_t)OUTSECT;            // 8 MB [B,H,Dh,L]
    __bf16* wti = vb + (size_t)OUTSECT;            // 6 MB
    __bf16* wto = wti + (size_t)N_QKV * KDIM;      // 2 MB

    cvt_all_k<<<3072, 256, 0, stream>>>(x, xb, W_in, wti, W_out, wto);

    gemm_bf<0, 4, 4><<<768, 256, 0, stream>>>(xb, wti, b_in,
        nullptr, kf, vf, qb, kb, vb, N_QKV / 128);

    attn_k<<<1024, 256, 0, stream>>>(qb, kb, vb, ob);

    gemm_bf<1, 4, 4><<<256, 256, 0, stream>>>(ob, wto, b_out,
        out, nullptr, nullptr, nullptr, nullptr, nullptr, DMODEL / 128);
}